// Round 12
// baseline (573.753 us; speedup 1.0000x reference)
//
#include <hip/hip_runtime.h>
#include <math.h>

#define N_NODES 10000
#define E_      320000
#define NT2     79                  // ceil(10000/128)
#define NPAD2   (NT2*128)           // 10112
#define NAF     (NPAD2*32)          // 323584 elements per af

// ---- small workspace area (float offsets) ----
#define S_HIST  1296              // 64*16 u32 -> [1296,2320)
#define ZERO_SMALL 2320
#define S_MMSLOT 2320             // 128 u32 (min[64], max[64])
#define S_MM    2448              // 2 u32
#define SMALL_END 2560

#define WS_BIG_END 7149736ull     // floats (~28.6 MB)

typedef __attribute__((ext_vector_type(8))) short bf16x8;
typedef __attribute__((ext_vector_type(4))) float f32x4;

__device__ __forceinline__ unsigned f2ord(float f){
  unsigned u = __float_as_uint(f);
  return (u & 0x80000000u) ? ~u : (u | 0x80000000u);
}
__device__ __forceinline__ float ord2f(unsigned u){
  return (u & 0x80000000u) ? __uint_as_float(u & 0x7FFFFFFFu) : __uint_as_float(~u);
}
__device__ __forceinline__ unsigned short f2bf(float f){   // RNE f32 -> bf16
  unsigned u = __float_as_uint(f);
  u = u + 0x7FFFu + ((u >> 16) & 1u);
  return (unsigned short)(u >> 16);
}

__global__ void init_k(float* ws, int* cnA, int* cnB, float* af1, float* af2){
  int i = blockIdx.x*blockDim.x + threadIdx.x;   // grid covers [0,10000)
  if(i < ZERO_SMALL) ws[i] = 0.f;
  if(i < 128){
    unsigned* sl = (unsigned*)(ws + S_MMSLOT);
    sl[i] = (i < 64) ? 0xFFFFFFFFu : 0u;
  }
  if(i < 2){
    unsigned* mm = (unsigned*)(ws + S_MM);
    mm[i] = (i==0) ? 0xFFFFFFFFu : 0u;
  }
  if(i < N_NODES){ cnA[i] = 0; cnB[i] = 0; }
  if(i < (NPAD2 - N_NODES)*32){     // zero af pad rows
    af1[N_NODES*32 + i] = 0.f;
    af2[N_NODES*32 + i] = 0.f;
  }
}

__global__ void zero_k(int* p, int n){
  int i = blockIdx.x*blockDim.x + threadIdx.x;
  if(i < n) p[i] = 0;
}

// LDS-privatized degree histogram: 16 blocks per graph
__global__ __launch_bounds__(256) void deg2_k(const int* __restrict__ dstA,
                                              const int* __restrict__ dstB,
                                              int* __restrict__ cntA,
                                              int* __restrict__ cntB, int E){
  __shared__ int h[N_NODES];
  for(int i=threadIdx.x;i<N_NODES;i+=256) h[i]=0;
  __syncthreads();
  int g = blockIdx.x >> 4;
  int chunk = blockIdx.x & 15;
  const int* dst = g ? dstB : dstA;
  int* cnt       = g ? cntB : cntA;
  int per = (E + 15)/16;
  int s = chunk*per, e = min(s+per, E);
  for(int i=s+threadIdx.x; i<e; i+=256) atomicAdd(&h[dst[i]], 1);
  __syncthreads();
  for(int i=threadIdx.x;i<N_NODES;i+=256){
    int v = h[i];
    if(v) atomicAdd(&cnt[i], v);
  }
}

// block b scans graph b: exclusive scan of int counts -> off[n+1], cur[n]; dinv/inv
__global__ void scan_k(const int* cn0, float* dv0, float* iv0, int* of0, int* cu0,
                       const int* cn1, float* dv1, float* iv1, int* of1, int* cu1, int n){
  const int* cnt = blockIdx.x ? cn1 : cn0;
  float* dinv    = blockIdx.x ? dv1 : dv0;
  float* inv     = blockIdx.x ? iv1 : iv0;
  int* off       = blockIdx.x ? of1 : of0;
  int* cur       = blockIdx.x ? cu1 : cu0;
  __shared__ int part[256];
  int t = threadIdx.x;
  int chunk = (n + 255)/256;
  int start = t*chunk, end = min(start+chunk, n);
  int s = 0;
  for(int i=start;i<end;i++) s += cnt[i];
  part[t] = s; __syncthreads();
  if(t==0){
    int run = 0;
    for(int i=0;i<256;i++){ int v=part[i]; part[i]=run; run+=v; }
  }
  __syncthreads();
  int run = part[t];
  for(int i=start;i<end;i++){
    off[i]=run; cur[i]=run; run += cnt[i];
  }
  if(end==n) off[n]=run;
  for(int i=start;i<end;i++){
    float d = (float)cnt[i] + 1.0f;
    dinv[i] = 1.0f/sqrtf(d);
    inv[i]  = 1.0f/d;
  }
}

__global__ void bucket_k(const int* __restrict__ eA, const int* __restrict__ eB,
                         int* curA, int* curB,
                         const float* __restrict__ dvA, const float* __restrict__ dvB,
                         int* __restrict__ srA, int* __restrict__ srB,
                         float* __restrict__ cfA, float* __restrict__ cfB,
                         int E, int nTot){
  int i = blockIdx.x*blockDim.x + threadIdx.x;
  if(i >= nTot) return;
  bool b = i >= E;
  int e = b ? i-E : i;
  const int* ei = b ? eB : eA;
  int* cur = b ? curB : curA;
  const float* dv = b ? dvB : dvA;
  int* ss = b ? srB : srA;
  float* cc = b ? cfB : cfA;
  int s = ei[e], d = ei[E+e];
  int pos = atomicAdd(&cur[d], 1);
  ss[pos] = s;
  cc[pos] = dv[s]*dv[d];
}

// C[n,FOUT] = act(A[n,FIN]) @ W[FIN,FOUT], 4 outputs/thread, dual-graph
template<int FIN, int FOUT, bool RELU>
__global__ __launch_bounds__(256) void gemm_k(const float* __restrict__ A0,
                                              const float* __restrict__ A1,
                                              const float* __restrict__ W,
                                              float* __restrict__ C0,
                                              float* __restrict__ C1,
                                              int n, int bpg){
  constexpr int KC  = (FIN > 64) ? 64 : FIN;
  constexpr int TPR = FOUT/4;
  constexpr int ROWS = 256/TPR;
  __shared__ float4 Ws[KC*TPR];
  bool gsel = blockIdx.x >= bpg;
  int blk = gsel ? blockIdx.x - bpg : blockIdx.x;
  const float* A = gsel ? A1 : A0;
  float* C       = gsel ? C1 : C0;
  int row = blk*ROWS + (int)threadIdx.x/TPR;
  int c4  = threadIdx.x % TPR;
  float4 acc = {0.f,0.f,0.f,0.f};
  const float4* W4 = (const float4*)W;
  for(int kc=0; kc<FIN; kc+=KC){
    __syncthreads();
    for(int t=threadIdx.x; t<KC*TPR; t+=256) Ws[t] = W4[(size_t)kc*TPR + t];
    __syncthreads();
    if(row < n){
      const float* a = A + (size_t)row*FIN + kc;
      #pragma unroll
      for(int k=0;k<KC;k++){
        float v = a[k];
        if(RELU) v = fmaxf(v, 0.f);
        float4 w = Ws[k*TPR + c4];
        acc.x = fmaf(v, w.x, acc.x);
        acc.y = fmaf(v, w.y, acc.y);
        acc.z = fmaf(v, w.z, acc.z);
        acc.w = fmaf(v, w.w, acc.w);
      }
    }
  }
  if(row < n) ((float4*)C)[(size_t)row*TPR + c4] = acc;
}

// fused gather-aggregation over a COLUMN SLICE (GC float4s of a GS-float4 row)
template<int GC, int GS, bool CVT>
__global__ __launch_bounds__(256) void aggr_k(const float* __restrict__ h0,
                                              const float* __restrict__ h1,
                                              const int* __restrict__ of0,
                                              const int* __restrict__ of1,
                                              const int* __restrict__ sr0,
                                              const int* __restrict__ sr1,
                                              const float* __restrict__ cf0,
                                              const float* __restrict__ cf1,
                                              const float* __restrict__ iv0,
                                              const float* __restrict__ iv1,
                                              const float* __restrict__ bias,
                                              float* __restrict__ o0,
                                              float* __restrict__ o1,
                                              unsigned short* __restrict__ H0,
                                              unsigned short* __restrict__ H1,
                                              int n, int bpg, int cOff){
  constexpr int NPB = 256/GC;
  bool gsel = blockIdx.x >= bpg;
  int blk = gsel ? blockIdx.x - bpg : blockIdx.x;
  const float* h = gsel ? h1 : h0;
  const int* off = gsel ? of1 : of0;
  const int* srcs = gsel ? sr1 : sr0;
  const float* cf = gsel ? cf1 : cf0;
  const float* inv = gsel ? iv1 : iv0;
  float* out = gsel ? o1 : o0;
  int node = blk*NPB + (int)threadIdx.x/GC;
  int g = (threadIdx.x % GC) + cOff;
  if(node >= n) return;
  const float4* h4 = (const float4*)h;
  float4 b4 = ((const float4*)bias)[g];
  float4 hv = h4[(size_t)node*GS + g];
  float iv = inv[node];
  float4 acc;
  acc.x = fmaf(hv.x, iv, b4.x);
  acc.y = fmaf(hv.y, iv, b4.y);
  acc.z = fmaf(hv.z, iv, b4.z);
  acc.w = fmaf(hv.w, iv, b4.w);
  int p = off[node], p1 = off[node+1];
  for(; p+4<=p1; p+=4){
    int s0=srcs[p], s1=srcs[p+1], s2=srcs[p+2], s3=srcs[p+3];
    float c0=cf[p], c1=cf[p+1], c2=cf[p+2], c3=cf[p+3];
    float4 v0=h4[(size_t)s0*GS+g], v1=h4[(size_t)s1*GS+g];
    float4 v2=h4[(size_t)s2*GS+g], v3=h4[(size_t)s3*GS+g];
    acc.x=fmaf(c0,v0.x,acc.x); acc.y=fmaf(c0,v0.y,acc.y); acc.z=fmaf(c0,v0.z,acc.z); acc.w=fmaf(c0,v0.w,acc.w);
    acc.x=fmaf(c1,v1.x,acc.x); acc.y=fmaf(c1,v1.y,acc.y); acc.z=fmaf(c1,v1.z,acc.z); acc.w=fmaf(c1,v1.w,acc.w);
    acc.x=fmaf(c2,v2.x,acc.x); acc.y=fmaf(c2,v2.y,acc.y); acc.z=fmaf(c2,v2.z,acc.z); acc.w=fmaf(c2,v2.w,acc.w);
    acc.x=fmaf(c3,v3.x,acc.x); acc.y=fmaf(c3,v3.y,acc.y); acc.z=fmaf(c3,v3.z,acc.z); acc.w=fmaf(c3,v3.w,acc.w);
  }
  for(; p<p1; ++p){
    int s = srcs[p];
    float c = cf[p];
    float4 v = h4[(size_t)s*GS + g];
    acc.x=fmaf(c,v.x,acc.x); acc.y=fmaf(c,v.y,acc.y);
    acc.z=fmaf(c,v.z,acc.z); acc.w=fmaf(c,v.w,acc.w);
  }
  ((float4*)out)[(size_t)node*GS + g] = acc;
  if(CVT){
    unsigned short* Hc = gsel ? H1 : H0;
    float vv[4] = {acc.x, acc.y, acc.z, acc.w};
    ushort4 hq, lq;
    unsigned short* hp = (unsigned short*)&hq;
    unsigned short* lp = (unsigned short*)&lq;
    #pragma unroll
    for(int j=0;j<4;j++){
      unsigned short hb = f2bf(vv[j]);
      float hf = __uint_as_float((unsigned)hb << 16);
      hp[j] = hb;
      lp[j] = f2bf(vv[j] - hf);
    }
    *(ushort4*)(Hc + (size_t)node*32 + g*4)       = hq;
    *(ushort4*)(Hc + NAF + (size_t)node*32 + g*4) = lq;
  }
}

// standalone bf16 split (small-ws fallback path only)
__global__ void cvt_k(const float* __restrict__ af1, const float* __restrict__ af2,
                      unsigned short* __restrict__ H){
  int i = blockIdx.x*256 + threadIdx.x;
  if(i >= 2*NAF) return;
  bool g = i >= NAF;
  int e = g ? i-NAF : i;
  float v = (g ? af2 : af1)[e];
  unsigned short h = f2bf(v);
  float hf = __uint_as_float((unsigned)h << 16);
  unsigned short l = f2bf(v - hf);
  unsigned short* Hp = H + (g ? 2*(size_t)NAF : 0);
  Hp[e] = h;
  Hp[e+NAF] = l;
}

// MFMA similarity v3: B-panel staged in LDS (shared by all 4 waves).
// Bs row layout: 144 B = hi[32 ushorts] | lo[32 ushorts] | pad 8 ushorts
// S = al*bl + al*bh + ah*bl + ah*bh via mfma_f32_16x16x32_bf16 (same term order).
template<bool HIST>
__global__ __launch_bounds__(256,2) void simm_k(const unsigned short* __restrict__ H,
                                                unsigned* __restrict__ mmslot,
                                                const unsigned* __restrict__ mm,
                                                unsigned* __restrict__ ghist){
  __shared__ __align__(16) unsigned short Bs[128*72];
  __shared__ unsigned lh[16*65];
  const unsigned short* h1 = H;
  const unsigned short* l1 = H + NAF;
  const unsigned short* h2 = H + 2*(size_t)NAF;
  const unsigned short* l2 = H + 3*(size_t)NAF;
  int bx = blockIdx.x % NT2, by = blockIdx.x / NT2;
  int i0 = by*128, j0 = bx*128;
  int lane = threadIdx.x & 63;
  int wv   = threadIdx.x >> 6;
  int r16  = lane & 15;
  int q    = lane >> 4;
  // stage B panel (hi+lo) to LDS: 1024 x 16B chunks
  for(int idx = threadIdx.x; idx < 1024; idx += 256){
    int row = idx >> 3, s8 = idx & 7;
    const unsigned short* src = (s8 < 4 ? h2 : l2) + (size_t)(j0+row)*32 + (s8&3)*8;
    *(float4*)(Bs + row*72 + s8*8) = *(const float4*)src;
  }
  // A fragments (held in regs)
  bf16x8 ah[2], al[2];
  #pragma unroll
  for(int t=0;t<2;t++){
    size_t row = i0 + wv*32 + t*16 + r16;
    ah[t] = *(const bf16x8*)(h1 + row*32 + q*8);
    al[t] = *(const bf16x8*)(l1 + row*32 + q*8);
  }
  __syncthreads();
  // B fragments from LDS (all upfront)
  bf16x8 bhf[8], blf[8];
  #pragma unroll
  for(int c=0;c<8;c++){
    const unsigned short* base = Bs + (c*16 + r16)*72 + q*8;
    bhf[c] = *(const bf16x8*)(base);
    blf[c] = *(const bf16x8*)(base + 32);
  }
  f32x4 acc[2][8];
  #pragma unroll
  for(int t=0;t<2;t++){
    #pragma unroll
    for(int c=0;c<8;c++){
      f32x4 v = {0.f,0.f,0.f,0.f};
      v = __builtin_amdgcn_mfma_f32_16x16x32_bf16(al[t], blf[c], v, 0,0,0);
      v = __builtin_amdgcn_mfma_f32_16x16x32_bf16(al[t], bhf[c], v, 0,0,0);
      v = __builtin_amdgcn_mfma_f32_16x16x32_bf16(ah[t], blf[c], v, 0,0,0);
      v = __builtin_amdgcn_mfma_f32_16x16x32_bf16(ah[t], bhf[c], v, 0,0,0);
      acc[t][c] = v;
    }
  }
  bool full = (i0+128 <= N_NODES) && (j0+128 <= N_NODES);
  int ibase = i0 + wv*32 + q*4;
  int jbase = j0 + r16;
  if(!HIST){
    float m = INFINITY, M = -INFINITY;
    #pragma unroll
    for(int t=0;t<2;t++){
      #pragma unroll
      for(int c=0;c<8;c++){
        #pragma unroll
        for(int r=0;r<4;r++){
          if(!full && (ibase + t*16 + r >= N_NODES || jbase + c*16 >= N_NODES)) continue;
          float v = acc[t][c][r];
          m = fminf(m, v); M = fmaxf(M, v);
        }
      }
    }
    #pragma unroll
    for(int off=32; off; off>>=1){
      m = fminf(m, __shfl_down(m, off, 64));
      M = fmaxf(M, __shfl_down(M, off, 64));
    }
    if(lane==0){
      int slot = (blockIdx.x*4 + wv) & 63;
      atomicMin(&mmslot[slot],    f2ord(m));
      atomicMax(&mmslot[64+slot], f2ord(M));
    }
  } else {
    float lo = ord2f(mm[0]);
    float hi = ord2f(mm[1]);
    float denom = (hi-lo) + 1e-12f;
    for(int t=threadIdx.x; t<16*65; t+=256) lh[t]=0u;
    __syncthreads();
    #pragma unroll
    for(int t=0;t<2;t++){
      #pragma unroll
      for(int c=0;c<8;c++){
        #pragma unroll
        for(int r=0;r<4;r++){
          if(!full && (ibase + t*16 + r >= N_NODES || jbase + c*16 >= N_NODES)) continue;
          int idx = (int)((acc[t][c][r]-lo)/denom*16.0f);   // reference op order
          idx = idx<0 ? 0 : (idx>15 ? 15 : idx);
          atomicAdd(&lh[idx*65 + lane], 1u);
        }
      }
    }
    __syncthreads();
    if(threadIdx.x<16){
      unsigned s=0;
      for(int w=0;w<64;w++) s += lh[threadIdx.x*65+w];
      atomicAdd(&ghist[(blockIdx.x & 63)*16 + threadIdx.x], s);
    }
  }
}

__global__ void mmred_k(float* ws){
  unsigned* sl = (unsigned*)(ws + S_MMSLOT);
  unsigned* mm = (unsigned*)(ws + S_MM);
  int t = threadIdx.x;   // 64 threads
  unsigned mn = sl[t], mx = sl[64+t];
  #pragma unroll
  for(int off=32; off; off>>=1){
    mn = min(mn, (unsigned)__shfl_down((int)mn, off, 64));
    mx = max(mx, (unsigned)__shfl_down((int)mx, off, 64));
  }
  if(t==0){ mm[0]=mn; mm[1]=mx; }
}

// 128 blocks: [0,64) graph1, [64,128) graph2. Writes partials PC[128][32] (no atomics).
__global__ void colsum_k(const float* __restrict__ af1, const float* __restrict__ af2,
                         float* __restrict__ PC, int n){
  bool g2 = blockIdx.x >= 64;
  const float* af = g2 ? af2 : af1;
  int blk = blockIdx.x & 63;
  int f = threadIdx.x % 32;
  int rg = threadIdx.x / 32;
  float acc = 0.f;
  for(int node = blk*8 + rg; node < n; node += 64*8)
    acc += af[(size_t)node*32 + f];
  __shared__ float s[256];
  s[threadIdx.x]=acc; __syncthreads();
  if(threadIdx.x<32){
    float v=0.f;
    for(int r=0;r<8;r++) v += s[r*32+threadIdx.x];
    PC[(int)blockIdx.x*32 + threadIdx.x] = v;
  }
}

// 80 blocks: [0,40) graph1, [40,80) graph2. csum reduced from PC in-block;
// writes attention-pool partials PA[80][32] (no atomics). One node per thread.
__global__ __launch_bounds__(256) void attpool_k(const float* __restrict__ af1,
                                                 const float* __restrict__ af2,
                                                 const float* __restrict__ att_w,
                                                 const float* __restrict__ PC,
                                                 float* __restrict__ PA, int n){
  bool g2 = blockIdx.x >= 40;
  const float* af = g2 ? af2 : af1;
  int blk = g2 ? blockIdx.x-40 : blockIdx.x;
  int tid = threadIdx.x;
  __shared__ float scs[32], sgc[32], swv[128];
  if(tid<32){
    float cs = 0.f;
    const float* pc = PC + (g2 ? 64*32 : 0);
    for(int r=0;r<64;r++) cs += pc[r*32+tid];
    scs[tid] = cs;
  }
  __syncthreads();
  if(tid<32){
    float acc = 0.f;
    for(int f=0;f<32;f++) acc += scs[f]*att_w[f*32+tid];
    sgc[tid] = tanhf(acc * (1.0f/N_NODES));
  }
  __syncthreads();
  float pacc[32];
  #pragma unroll
  for(int f=0;f<32;f++) pacc[f]=0.f;
  int node = blk*256 + tid;
  if(node < n){
    const float* row = af + (size_t)node*32;
    float d = 0.f;
    #pragma unroll
    for(int f=0;f<32;f++) d += row[f]*sgc[f];
    float sig = 1.0f/(1.0f+expf(-d));
    #pragma unroll
    for(int f=0;f<32;f++) pacc[f] = row[f]*sig;
  }
  int wv = tid >> 6, lane = tid & 63;
  #pragma unroll
  for(int f=0;f<32;f++){
    float v = pacc[f];
    for(int off=32; off; off>>=1) v += __shfl_down(v, off, 64);
    if(lane==0) swv[wv*32+f] = v;
  }
  __syncthreads();
  if(tid<32)
    PA[(int)blockIdx.x*32 + tid] = swv[tid] + swv[32+tid] + swv[64+tid] + swv[96+tid];
}

// 80 blocks: [0,40) -> af1 with pv=p2 (PA rows 40..79) -> PT rows 0..39;
//            [40,80) -> af2 with pv=p1 (PA rows 0..39) -> PT rows 40..79.
__global__ __launch_bounds__(256) void tnmean_k(const float* __restrict__ af1,
                                                const float* __restrict__ af2,
                                                const float* __restrict__ tn_w,
                                                const float* __restrict__ tn_wb,
                                                const float* __restrict__ tn_bias,
                                                const float* __restrict__ PA,
                                                float* __restrict__ PT, int n){
  bool g2 = blockIdx.x >= 40;
  const float* X = g2 ? af2 : af1;
  int blk = g2 ? blockIdx.x-40 : blockIdx.x;
  int tid = threadIdx.x;
  __shared__ float spv[32];
  __shared__ float sB[512];
  __shared__ float sc[16];
  __shared__ float swn[64];
  if(tid<32){
    float s = 0.f;
    const float* pa = PA + (g2 ? 0 : 40*32);   // g1 blocks use p2, g2 blocks use p1
    for(int r=0;r<40;r++) s += pa[r*32+tid];
    spv[tid] = s;
  }
  __syncthreads();
  for(int e=tid; e<512; e+=256){
    int g = e/16, k = e%16;
    float acc = 0.f;
    for(int f=0;f<32;f++) acc += tn_w[(g*32+f)*16+k]*spv[f];
    sB[e] = acc + tn_wb[k*64+g];
  }
  if(tid<16){
    float acc = 0.f;
    for(int f=0;f<32;f++) acc += tn_wb[tid*64+32+f]*spv[f];
    sc[tid] = acc + tn_bias[tid];
  }
  __syncthreads();
  float a[16];
  #pragma unroll
  for(int k=0;k<16;k++) a[k]=0.f;
  int node = blk*256 + tid;
  if(node < n){
    const float* row = X + (size_t)node*32;
    float rv[32];
    #pragma unroll
    for(int g=0;g<32;g++) rv[g]=row[g];
    #pragma unroll
    for(int k=0;k<16;k++){
      float y = sc[k];
      #pragma unroll
      for(int g=0;g<32;g++) y += rv[g]*sB[g*16+k];
      a[k] = fmaxf(y, 0.f);
    }
  }
  int wv = tid >> 6, lane = tid & 63;
  #pragma unroll
  for(int k=0;k<16;k++){
    float v = a[k];
    for(int off=32; off; off>>=1) v += __shfl_down(v, off, 64);
    if(lane==0) swn[wv*16+k] = v;
  }
  __syncthreads();
  if(tid<16)
    PT[(int)blockIdx.x*16 + tid] = swn[tid] + swn[16+tid] + swn[32+tid] + swn[48+tid];
}

// parallel head: 64 threads, 1 block; reduces PA->p1/p2 and PT->s1/s2; s0 inline
__global__ void final_k(const float* __restrict__ PA, const float* __restrict__ PT,
                        const unsigned* __restrict__ ghist,
                        const float* __restrict__ tn_w, const float* __restrict__ tn_wb,
                        const float* __restrict__ tn_bias,
                        const float* __restrict__ fc1_w, const float* __restrict__ fc1_b,
                        const float* __restrict__ fc2_w, const float* __restrict__ fc2_b,
                        float* __restrict__ out){
  __shared__ float sp1[32], sp2[32];
  __shared__ float sc[64];
  __shared__ float hraw[16];
  __shared__ float sh[16];
  int t = threadIdx.x;
  const float invN = 1.0f/N_NODES;
  if(t<32){
    float s = 0.f;
    for(int r=0;r<40;r++) s += PA[r*32+t];
    sp1[t] = s;
  } else {
    int j = t-32;
    float s = 0.f;
    for(int r=40;r<80;r++) s += PA[r*32+j];
    sp2[j] = s;
  }
  __syncthreads();
  if(t<16){
    float s = 0.f;
    for(int f1=0;f1<32;f1++){
      float a = sp1[f1];
      for(int f2=0;f2<32;f2++) s += a*tn_w[(f1*32+f2)*16+t]*sp2[f2];
    }
    float blk = 0.f;
    for(int f=0;f<32;f++) blk += tn_wb[t*64+f]*sp1[f] + tn_wb[t*64+32+f]*sp2[f];
    sc[t] = fmaxf(s + blk + tn_bias[t], 0.f);
  }
  else if(t<32){
    int k = t-16;
    float s = 0.f;
    for(int r=0;r<40;r++) s += PT[r*16+k];
    sc[t] = s*invN;
  }
  else if(t<48){
    int k = t-32;
    float s = 0.f;
    for(int r=40;r<80;r++) s += PT[r*16+k];
    sc[t] = s*invN;
  }
  int bin = t & 15, grp = t >> 4;
  unsigned c = 0;
  for(int s=grp; s<64; s+=4) c += ghist[s*16+bin];
  c += (unsigned)__shfl_down((int)c, 32, 64);
  c += (unsigned)__shfl_down((int)c, 16, 64);
  if(t<16){
    float v = (float)c;
    if(v > 16777216.0f) v = 16777216.0f;   // fp32 +1.0 saturation emulation
    hraw[t] = v;
  }
  __syncthreads();
  if(t<16){
    float tot = 0.f;
    for(int b=0;b<16;b++) tot += hraw[b];   // same serial order as reference
    sc[48+t] = hraw[t]/tot;
  }
  __syncthreads();
  if(t<16){
    float a = fc1_b[t];
    for(int i=0;i<64;i++) a += sc[i]*fc1_w[i*16+t];
    sh[t] = fmaxf(a, 0.f);
  }
  __syncthreads();
  if(t==0){
    float o = fc2_b[0];
    for(int j=0;j<16;j++) o += sh[j]*fc2_w[j];
    out[0] = 1.0f/(1.0f+expf(-o));
  }
}

extern "C" void kernel_launch(void* const* d_in, const int* in_sizes, int n_in,
                              void* d_out, int out_size, void* d_ws, size_t ws_size,
                              hipStream_t stream){
  const float* x1      = (const float*)d_in[0];
  const float* x2      = (const float*)d_in[1];
  const int*   ei1     = (const int*)d_in[2];
  const int*   ei2     = (const int*)d_in[3];
  const float* W1      = (const float*)d_in[4];
  const float* b1      = (const float*)d_in[5];
  const float* W2      = (const float*)d_in[6];
  const float* b2      = (const float*)d_in[7];
  const float* W3      = (const float*)d_in[8];
  const float* b3      = (const float*)d_in[9];
  const float* att_w   = (const float*)d_in[10];
  const float* tn_w    = (const float*)d_in[11];
  const float* tn_wb   = (const float*)d_in[12];
  const float* tn_bias = (const float*)d_in[13];
  const float* fc1_w   = (const float*)d_in[14];
  const float* fc1_b   = (const float*)d_in[15];
  const float* fc2_w   = (const float*)d_in[16];
  const float* fc2_b   = (const float*)d_in[17];

  float* ws = (float*)d_ws;
  float* out = (float*)d_out;
  const int N = N_NODES, E = E_;

  bool big = ws_size >= WS_BIG_END*sizeof(float);

  size_t oCN1,oCN2,oDV1,oDV2,oIV1,oIV2,oOF1,oOF2,oCU1,oCU2,oSR1,oSR2,
         oCF1,oCF2,oBH1,oBH2,oBO1,oBO2,oAF1,oAF2;
  if(big){
    oCN1=2560;    oCN2=12560;   oDV1=22560;   oDV2=32560;
    oIV1=42560;   oIV2=52560;   oOF1=62560;   oOF2=72564;
    oCU1=82568;   oCU2=92568;   oSR1=102568;  oSR2=422568;
    oCF1=742568;  oCF2=1062568; oBH1=1382568; oBH2=2662568;
    oBO1=3942568; oBO2=5222568; oAF1=6502568; oAF2=6826152;
  } else {
    oCN1=2560;    oCN2=oCN1;    oDV1=12560;   oDV2=oDV1;
    oIV1=22560;   oIV2=oIV1;    oOF1=32560;   oOF2=oOF1;
    oCU1=42564;   oCU2=oCU1;    oSR1=52564;   oSR2=oSR1;
    oCF1=372564;  oCF2=oCF1;    oBH1=692564;  oBH2=oBH1;
    oBO1=1972564; oBO2=oBO1;    oAF1=3252564; oAF2=3576148;
  }
  int* cn1=(int*)(ws+oCN1); int* cn2=(int*)(ws+oCN2);
  float* dv1=ws+oDV1; float* dv2=ws+oDV2;
  float* iv1=ws+oIV1; float* iv2=ws+oIV2;
  int* of1=(int*)(ws+oOF1); int* of2=(int*)(ws+oOF2);
  int* cu1=(int*)(ws+oCU1); int* cu2=(int*)(ws+oCU2);
  int* sr1=(int*)(ws+oSR1); int* sr2=(int*)(ws+oSR2);
  float* cf1=ws+oCF1; float* cf2=ws+oCF2;
  float* bh1=ws+oBH1; float* bh2=ws+oBH2;
  float* bo1=ws+oBO1; float* bo2=ws+oBO2;
  float* af1=ws+oAF1; float* af2=ws+oAF2;
  // big: H lives in bo1 (dead after gemm3); small: in bh1 (dead after loop)
  unsigned short* Hbf = (unsigned short*)(big ? bo1 : bh1);
  // tail partials live in dead GCN scratch: big -> bh1, small -> bo1
  float* part = big ? bh1 : bo1;
  float* PC = part;                 // 128*32
  float* PA = part + 4096;          // 80*32
  float* PT = part + 4096 + 2560;   // 80*16

  unsigned* mmslot = (unsigned*)(ws + S_MMSLOT);
  unsigned* mm     = (unsigned*)(ws + S_MM);
  unsigned* ghist  = (unsigned*)(ws + S_HIST);

  const int BPG1 = 1250;   // gemm F=128 (ROWS=8)
  const int BPG2 = 625;    // gemm F=64
  const int BPG3 = 313;    // gemm F=32
  const int BA16 = 625;    // aggr GC=16 (16 nodes/block)
  const int BA8  = 313;    // aggr GC=8  (32 nodes/block)
  unsigned short* Z = (unsigned short*)0;

  init_k<<<(N+255)/256, 256, 0, stream>>>(ws, cn1, cn2, af1, af2);

  if(big){
    deg2_k<<<32, 256, 0, stream>>>(ei1+E, ei2+E, cn1, cn2, E);
    scan_k<<<2, 256, 0, stream>>>(cn1, dv1, iv1, of1, cu1,
                                  cn2, dv2, iv2, of2, cu2, N);
    bucket_k<<<(2*E+255)/256, 256, 0, stream>>>(ei1, ei2, cu1, cu2, dv1, dv2,
                                                sr1, sr2, cf1, cf2, E, 2*E);
    gemm_k<128,128,false><<<2*BPG1, 256, 0, stream>>>(x1, x2, W1, bh1, bh2, N, BPG1);
    aggr_k<16,32,false><<<BA16, 256, 0, stream>>>(bh1,bh1, of1,of1, sr1,sr1, cf1,cf1,
                                                  iv1,iv1, b1, bo1,bo1, Z,Z, N, BA16, 0);
    aggr_k<16,32,false><<<BA16, 256, 0, stream>>>(bh1,bh1, of1,of1, sr1,sr1, cf1,cf1,
                                                  iv1,iv1, b1, bo1,bo1, Z,Z, N, BA16, 16);
    aggr_k<16,32,false><<<BA16, 256, 0, stream>>>(bh2,bh2, of2,of2, sr2,sr2, cf2,cf2,
                                                  iv2,iv2, b1, bo2,bo2, Z,Z, N, BA16, 0);
    aggr_k<16,32,false><<<BA16, 256, 0, stream>>>(bh2,bh2, of2,of2, sr2,sr2, cf2,cf2,
                                                  iv2,iv2, b1, bo2,bo2, Z,Z, N, BA16, 16);
    gemm_k<128,64,true><<<2*BPG2, 256, 0, stream>>>(bo1, bo2, W2, bh1, bh2, N, BPG2);
    aggr_k<16,16,false><<<BA16, 256, 0, stream>>>(bh1,bh1, of1,of1, sr1,sr1, cf1,cf1,
                                                  iv1,iv1, b2, bo1,bo1, Z,Z, N, BA16, 0);
    aggr_k<16,16,false><<<BA16, 256, 0, stream>>>(bh2,bh2, of2,of2, sr2,sr2, cf2,cf2,
                                                  iv2,iv2, b2, bo2,bo2, Z,Z, N, BA16, 0);
    gemm_k<64,32,true><<<2*BPG3, 256, 0, stream>>>(bo1, bo2, W3, bh1, bh2, N, BPG3);
    aggr_k<8,8,true><<<2*BA8, 256, 0, stream>>>(bh1,bh2, of1,of2, sr1,sr2, cf1,cf2,
                                                iv1,iv2, b3, af1,af2,
                                                Hbf, Hbf + 2*(size_t)NAF, N, BA8, 0);
  } else {
    for(int g=0; g<2; g++){
      const float* x = g ? x2 : x1;
      const int* ei  = g ? ei2 : ei1;
      float* af      = g ? af2 : af1;
      if(g) zero_k<<<(N+255)/256, 256, 0, stream>>>(cn1, N);
      deg2_k<<<16, 256, 0, stream>>>(ei+E, ei+E, cn1, cn1, E);
      scan_k<<<1, 256, 0, stream>>>(cn1, dv1, iv1, of1, cu1,
                                    cn1, dv1, iv1, of1, cu1, N);
      bucket_k<<<(E+255)/256, 256, 0, stream>>>(ei, ei, cu1, cu1, dv1, dv1,
                                                sr1, sr1, cf1, cf1, E, E);
      gemm_k<128,128,false><<<BPG1, 256, 0, stream>>>(x, x, W1, bh1, bh1, N, BPG1);
      aggr_k<16,32,false><<<BA16, 256, 0, stream>>>(bh1,bh1, of1,of1, sr1,sr1, cf1,cf1,
                                                    iv1,iv1, b1, bo1,bo1, Z,Z, N, BA16, 0);
      aggr_k<16,32,false><<<BA16, 256, 0, stream>>>(bh1,bh1, of1,of1, sr1,sr1, cf1,cf1,
                                                    iv1,iv1, b1, bo1,bo1, Z,Z, N, BA16, 16);
      gemm_k<128,64,true><<<BPG2, 256, 0, stream>>>(bo1, bo1, W2, bh1, bh1, N, BPG2);
      aggr_k<16,16,false><<<BA16, 256, 0, stream>>>(bh1,bh1, of1,of1, sr1,sr1, cf1,cf1,
                                                    iv1,iv1, b2, bo1,bo1, Z,Z, N, BA16, 0);
      gemm_k<64,32,true><<<BPG3, 256, 0, stream>>>(bo1, bo1, W3, bh1, bh1, N, BPG3);
      aggr_k<8,8,false><<<BA8, 256, 0, stream>>>(bh1,bh1, of1,of1, sr1,sr1, cf1,cf1,
                                                 iv1,iv1, b3, af,af, Z,Z, N, BA8, 0);
    }
    cvt_k<<<(2*NAF+255)/256, 256, 0, stream>>>(af1, af2, Hbf);
  }

  // similarity on matrix cores: min/max pass -> slot reduce -> histogram pass
  simm_k<false><<<NT2*NT2, 256, 0, stream>>>(Hbf, mmslot, mm, ghist);
  mmred_k<<<1, 64, 0, stream>>>(ws);
  simm_k<true ><<<NT2*NT2, 256, 0, stream>>>(Hbf, mmslot, mm, ghist);

  // tail: partial-sum pipeline, no hot atomics
  colsum_k<<<128, 256, 0, stream>>>(af1, af2, PC, N);
  attpool_k<<<80, 256, 0, stream>>>(af1, af2, att_w, PC, PA, N);
  tnmean_k<<<80, 256, 0, stream>>>(af1, af2, tn_w, tn_wb, tn_bias, PA, PT, N);
  final_k<<<1, 64, 0, stream>>>(PA, PT, ghist, tn_w, tn_wb, tn_bias,
                                fc1_w, fc1_b, fc2_w, fc2_b, out);
}

// Round 13
// 490.285 us; speedup vs baseline: 1.1702x; 1.1702x over previous
//
#include <hip/hip_runtime.h>
#include <math.h>

#define N_NODES 10000
#define E_      320000
#define NT2     79                  // ceil(10000/128)
#define NJS     20                  // ceil(79/4) j-strips of 4 tiles
#define NPAD2   (NT2*128)           // 10112
#define NAF     (NPAD2*32)          // 323584 elements per af

// ---- small workspace area (float offsets) ----
#define S_HIST  1296              // 64*16 u32 -> [1296,2320)
#define ZERO_SMALL 2320
#define S_MMSLOT 2320             // 128 u32 (min[64], max[64])
#define S_MM    2448              // 2 u32
#define SMALL_END 2560

#define WS_BIG_END 7149736ull     // floats (~28.6 MB)

typedef __attribute__((ext_vector_type(8))) short bf16x8;
typedef __attribute__((ext_vector_type(4))) float f32x4;

__device__ __forceinline__ unsigned f2ord(float f){
  unsigned u = __float_as_uint(f);
  return (u & 0x80000000u) ? ~u : (u | 0x80000000u);
}
__device__ __forceinline__ float ord2f(unsigned u){
  return (u & 0x80000000u) ? __uint_as_float(u & 0x7FFFFFFFu) : __uint_as_float(~u);
}
__device__ __forceinline__ unsigned short f2bf(float f){   // RNE f32 -> bf16
  unsigned u = __float_as_uint(f);
  u = u + 0x7FFFu + ((u >> 16) & 1u);
  return (unsigned short)(u >> 16);
}

__global__ void init_k(float* ws, int* cnA, int* cnB, float* af1, float* af2){
  int i = blockIdx.x*blockDim.x + threadIdx.x;   // grid covers [0,10000)
  if(i < ZERO_SMALL) ws[i] = 0.f;
  if(i < 128){
    unsigned* sl = (unsigned*)(ws + S_MMSLOT);
    sl[i] = (i < 64) ? 0xFFFFFFFFu : 0u;
  }
  if(i < 2){
    unsigned* mm = (unsigned*)(ws + S_MM);
    mm[i] = (i==0) ? 0xFFFFFFFFu : 0u;
  }
  if(i < N_NODES){ cnA[i] = 0; cnB[i] = 0; }
  if(i < (NPAD2 - N_NODES)*32){     // zero af pad rows
    af1[N_NODES*32 + i] = 0.f;
    af2[N_NODES*32 + i] = 0.f;
  }
}

__global__ void zero_k(int* p, int n){
  int i = blockIdx.x*blockDim.x + threadIdx.x;
  if(i < n) p[i] = 0;
}

// LDS-privatized degree histogram: 16 blocks per graph
__global__ __launch_bounds__(256) void deg2_k(const int* __restrict__ dstA,
                                              const int* __restrict__ dstB,
                                              int* __restrict__ cntA,
                                              int* __restrict__ cntB, int E){
  __shared__ int h[N_NODES];
  for(int i=threadIdx.x;i<N_NODES;i+=256) h[i]=0;
  __syncthreads();
  int g = blockIdx.x >> 4;
  int chunk = blockIdx.x & 15;
  const int* dst = g ? dstB : dstA;
  int* cnt       = g ? cntB : cntA;
  int per = (E + 15)/16;
  int s = chunk*per, e = min(s+per, E);
  for(int i=s+threadIdx.x; i<e; i+=256) atomicAdd(&h[dst[i]], 1);
  __syncthreads();
  for(int i=threadIdx.x;i<N_NODES;i+=256){
    int v = h[i];
    if(v) atomicAdd(&cnt[i], v);
  }
}

// block b scans graph b: exclusive scan of int counts -> off[n+1], cur[n]; dinv/inv
__global__ void scan_k(const int* cn0, float* dv0, float* iv0, int* of0, int* cu0,
                       const int* cn1, float* dv1, float* iv1, int* of1, int* cu1, int n){
  const int* cnt = blockIdx.x ? cn1 : cn0;
  float* dinv    = blockIdx.x ? dv1 : dv0;
  float* inv     = blockIdx.x ? iv1 : iv0;
  int* off       = blockIdx.x ? of1 : of0;
  int* cur       = blockIdx.x ? cu1 : cu0;
  __shared__ int part[256];
  int t = threadIdx.x;
  int chunk = (n + 255)/256;
  int start = t*chunk, end = min(start+chunk, n);
  int s = 0;
  for(int i=start;i<end;i++) s += cnt[i];
  part[t] = s; __syncthreads();
  if(t==0){
    int run = 0;
    for(int i=0;i<256;i++){ int v=part[i]; part[i]=run; run+=v; }
  }
  __syncthreads();
  int run = part[t];
  for(int i=start;i<end;i++){
    off[i]=run; cur[i]=run; run += cnt[i];
  }
  if(end==n) off[n]=run;
  for(int i=start;i<end;i++){
    float d = (float)cnt[i] + 1.0f;
    dinv[i] = 1.0f/sqrtf(d);
    inv[i]  = 1.0f/d;
  }
}

__global__ void bucket_k(const int* __restrict__ eA, const int* __restrict__ eB,
                         int* curA, int* curB,
                         const float* __restrict__ dvA, const float* __restrict__ dvB,
                         int* __restrict__ srA, int* __restrict__ srB,
                         float* __restrict__ cfA, float* __restrict__ cfB,
                         int E, int nTot){
  int i = blockIdx.x*blockDim.x + threadIdx.x;
  if(i >= nTot) return;
  bool b = i >= E;
  int e = b ? i-E : i;
  const int* ei = b ? eB : eA;
  int* cur = b ? curB : curA;
  const float* dv = b ? dvB : dvA;
  int* ss = b ? srB : srA;
  float* cc = b ? cfB : cfA;
  int s = ei[e], d = ei[E+e];
  int pos = atomicAdd(&cur[d], 1);
  ss[pos] = s;
  cc[pos] = dv[s]*dv[d];
}

// C[n,FOUT] = act(A[n,FIN]) @ W[FIN,FOUT], 4 outputs/thread, dual-graph
template<int FIN, int FOUT, bool RELU>
__global__ __launch_bounds__(256) void gemm_k(const float* __restrict__ A0,
                                              const float* __restrict__ A1,
                                              const float* __restrict__ W,
                                              float* __restrict__ C0,
                                              float* __restrict__ C1,
                                              int n, int bpg){
  constexpr int KC  = (FIN > 64) ? 64 : FIN;
  constexpr int TPR = FOUT/4;
  constexpr int ROWS = 256/TPR;
  __shared__ float4 Ws[KC*TPR];
  bool gsel = blockIdx.x >= bpg;
  int blk = gsel ? blockIdx.x - bpg : blockIdx.x;
  const float* A = gsel ? A1 : A0;
  float* C       = gsel ? C1 : C0;
  int row = blk*ROWS + (int)threadIdx.x/TPR;
  int c4  = threadIdx.x % TPR;
  float4 acc = {0.f,0.f,0.f,0.f};
  const float4* W4 = (const float4*)W;
  for(int kc=0; kc<FIN; kc+=KC){
    __syncthreads();
    for(int t=threadIdx.x; t<KC*TPR; t+=256) Ws[t] = W4[(size_t)kc*TPR + t];
    __syncthreads();
    if(row < n){
      const float* a = A + (size_t)row*FIN + kc;
      #pragma unroll
      for(int k=0;k<KC;k++){
        float v = a[k];
        if(RELU) v = fmaxf(v, 0.f);
        float4 w = Ws[k*TPR + c4];
        acc.x = fmaf(v, w.x, acc.x);
        acc.y = fmaf(v, w.y, acc.y);
        acc.z = fmaf(v, w.z, acc.z);
        acc.w = fmaf(v, w.w, acc.w);
      }
    }
  }
  if(row < n) ((float4*)C)[(size_t)row*TPR + c4] = acc;
}

// fused gather-aggregation over a COLUMN SLICE (GC float4s of a GS-float4 row)
template<int GC, int GS, bool CVT>
__global__ __launch_bounds__(256) void aggr_k(const float* __restrict__ h0,
                                              const float* __restrict__ h1,
                                              const int* __restrict__ of0,
                                              const int* __restrict__ of1,
                                              const int* __restrict__ sr0,
                                              const int* __restrict__ sr1,
                                              const float* __restrict__ cf0,
                                              const float* __restrict__ cf1,
                                              const float* __restrict__ iv0,
                                              const float* __restrict__ iv1,
                                              const float* __restrict__ bias,
                                              float* __restrict__ o0,
                                              float* __restrict__ o1,
                                              unsigned short* __restrict__ H0,
                                              unsigned short* __restrict__ H1,
                                              int n, int bpg, int cOff){
  constexpr int NPB = 256/GC;
  bool gsel = blockIdx.x >= bpg;
  int blk = gsel ? blockIdx.x - bpg : blockIdx.x;
  const float* h = gsel ? h1 : h0;
  const int* off = gsel ? of1 : of0;
  const int* srcs = gsel ? sr1 : sr0;
  const float* cf = gsel ? cf1 : cf0;
  const float* inv = gsel ? iv1 : iv0;
  float* out = gsel ? o1 : o0;
  int node = blk*NPB + (int)threadIdx.x/GC;
  int g = (threadIdx.x % GC) + cOff;
  if(node >= n) return;
  const float4* h4 = (const float4*)h;
  float4 b4 = ((const float4*)bias)[g];
  float4 hv = h4[(size_t)node*GS + g];
  float iv = inv[node];
  float4 acc;
  acc.x = fmaf(hv.x, iv, b4.x);
  acc.y = fmaf(hv.y, iv, b4.y);
  acc.z = fmaf(hv.z, iv, b4.z);
  acc.w = fmaf(hv.w, iv, b4.w);
  int p = off[node], p1 = off[node+1];
  for(; p+4<=p1; p+=4){
    int s0=srcs[p], s1=srcs[p+1], s2=srcs[p+2], s3=srcs[p+3];
    float c0=cf[p], c1=cf[p+1], c2=cf[p+2], c3=cf[p+3];
    float4 v0=h4[(size_t)s0*GS+g], v1=h4[(size_t)s1*GS+g];
    float4 v2=h4[(size_t)s2*GS+g], v3=h4[(size_t)s3*GS+g];
    acc.x=fmaf(c0,v0.x,acc.x); acc.y=fmaf(c0,v0.y,acc.y); acc.z=fmaf(c0,v0.z,acc.z); acc.w=fmaf(c0,v0.w,acc.w);
    acc.x=fmaf(c1,v1.x,acc.x); acc.y=fmaf(c1,v1.y,acc.y); acc.z=fmaf(c1,v1.z,acc.z); acc.w=fmaf(c1,v1.w,acc.w);
    acc.x=fmaf(c2,v2.x,acc.x); acc.y=fmaf(c2,v2.y,acc.y); acc.z=fmaf(c2,v2.z,acc.z); acc.w=fmaf(c2,v2.w,acc.w);
    acc.x=fmaf(c3,v3.x,acc.x); acc.y=fmaf(c3,v3.y,acc.y); acc.z=fmaf(c3,v3.z,acc.z); acc.w=fmaf(c3,v3.w,acc.w);
  }
  for(; p<p1; ++p){
    int s = srcs[p];
    float c = cf[p];
    float4 v = h4[(size_t)s*GS + g];
    acc.x=fmaf(c,v.x,acc.x); acc.y=fmaf(c,v.y,acc.y);
    acc.z=fmaf(c,v.z,acc.z); acc.w=fmaf(c,v.w,acc.w);
  }
  ((float4*)out)[(size_t)node*GS + g] = acc;
  if(CVT){
    unsigned short* Hc = gsel ? H1 : H0;
    float vv[4] = {acc.x, acc.y, acc.z, acc.w};
    ushort4 hq, lq;
    unsigned short* hp = (unsigned short*)&hq;
    unsigned short* lp = (unsigned short*)&lq;
    #pragma unroll
    for(int j=0;j<4;j++){
      unsigned short hb = f2bf(vv[j]);
      float hf = __uint_as_float((unsigned)hb << 16);
      hp[j] = hb;
      lp[j] = f2bf(vv[j] - hf);
    }
    *(ushort4*)(Hc + (size_t)node*32 + g*4)       = hq;
    *(ushort4*)(Hc + NAF + (size_t)node*32 + g*4) = lq;
  }
}

// standalone bf16 split (small-ws fallback path only)
__global__ void cvt_k(const float* __restrict__ af1, const float* __restrict__ af2,
                      unsigned short* __restrict__ H){
  int i = blockIdx.x*256 + threadIdx.x;
  if(i >= 2*NAF) return;
  bool g = i >= NAF;
  int e = g ? i-NAF : i;
  float v = (g ? af2 : af1)[e];
  unsigned short h = f2bf(v);
  float hf = __uint_as_float((unsigned)h << 16);
  unsigned short l = f2bf(v - hf);
  unsigned short* Hp = H + (g ? 2*(size_t)NAF : 0);
  Hp[e] = h;
  Hp[e+NAF] = l;
}

// MFMA similarity v4: 128x512 strip per block (4 j-tiles), B restaged per tile.
// Grid = NT2 * NJS = 1580 blocks (4x fewer dispatches than per-tile grids).
// S = al*bl + al*bh + ah*bl + ah*bh via mfma_f32_16x16x32_bf16 (same term order).
template<bool HIST>
__global__ __launch_bounds__(256,2) void simm_k(const unsigned short* __restrict__ H,
                                                unsigned* __restrict__ mmslot,
                                                const unsigned* __restrict__ mm,
                                                unsigned* __restrict__ ghist){
  __shared__ __align__(16) unsigned short Bs[128*72];
  __shared__ unsigned lh[16*65];
  const unsigned short* h1 = H;
  const unsigned short* l1 = H + NAF;
  const unsigned short* h2 = H + 2*(size_t)NAF;
  const unsigned short* l2 = H + 3*(size_t)NAF;
  int by = blockIdx.x % NT2;
  int js = blockIdx.x / NT2;
  int i0 = by*128;
  int lane = threadIdx.x & 63;
  int wv   = threadIdx.x >> 6;
  int r16  = lane & 15;
  int q    = lane >> 4;
  // A fragments loaded once for the whole strip
  bf16x8 ah[2], al[2];
  #pragma unroll
  for(int t=0;t<2;t++){
    size_t row = i0 + wv*32 + t*16 + r16;
    ah[t] = *(const bf16x8*)(h1 + row*32 + q*8);
    al[t] = *(const bf16x8*)(l1 + row*32 + q*8);
  }
  float mMin = INFINITY, mMax = -INFINITY;
  float lo = 0.f, denom = 1.f;
  if(HIST){
    lo = ord2f(mm[0]);
    float hi = ord2f(mm[1]);
    denom = (hi-lo) + 1e-12f;
    for(int t=threadIdx.x; t<16*65; t+=256) lh[t]=0u;
  }
  int ibase = i0 + wv*32 + q*4;
  bool rowfull = (i0+128 <= N_NODES);
  int jtEnd = min(js*4+4, NT2);
  for(int jt = js*4; jt < jtEnd; ++jt){
    int j0 = jt*128;
    __syncthreads();   // Bs safe to overwrite (also covers lh zeroing on first iter)
    for(int idx = threadIdx.x; idx < 1024; idx += 256){
      int row = idx >> 3, s8 = idx & 7;
      const unsigned short* src = (s8 < 4 ? h2 : l2) + (size_t)(j0+row)*32 + (s8&3)*8;
      *(float4*)(Bs + row*72 + s8*8) = *(const float4*)src;
    }
    __syncthreads();
    bf16x8 bhf[8], blf[8];
    #pragma unroll
    for(int c=0;c<8;c++){
      const unsigned short* base = Bs + (c*16 + r16)*72 + q*8;
      bhf[c] = *(const bf16x8*)(base);
      blf[c] = *(const bf16x8*)(base + 32);
    }
    f32x4 acc[2][8];
    #pragma unroll
    for(int t=0;t<2;t++){
      #pragma unroll
      for(int c=0;c<8;c++){
        f32x4 v = {0.f,0.f,0.f,0.f};
        v = __builtin_amdgcn_mfma_f32_16x16x32_bf16(al[t], blf[c], v, 0,0,0);
        v = __builtin_amdgcn_mfma_f32_16x16x32_bf16(al[t], bhf[c], v, 0,0,0);
        v = __builtin_amdgcn_mfma_f32_16x16x32_bf16(ah[t], blf[c], v, 0,0,0);
        v = __builtin_amdgcn_mfma_f32_16x16x32_bf16(ah[t], bhf[c], v, 0,0,0);
        acc[t][c] = v;
      }
    }
    bool full = rowfull && (j0+128 <= N_NODES);
    int jbase = j0 + r16;
    if(!HIST){
      #pragma unroll
      for(int t=0;t<2;t++){
        #pragma unroll
        for(int c=0;c<8;c++){
          #pragma unroll
          for(int r=0;r<4;r++){
            if(!full && (ibase + t*16 + r >= N_NODES || jbase + c*16 >= N_NODES)) continue;
            float v = acc[t][c][r];
            mMin = fminf(mMin, v); mMax = fmaxf(mMax, v);
          }
        }
      }
    } else {
      #pragma unroll
      for(int t=0;t<2;t++){
        #pragma unroll
        for(int c=0;c<8;c++){
          #pragma unroll
          for(int r=0;r<4;r++){
            if(!full && (ibase + t*16 + r >= N_NODES || jbase + c*16 >= N_NODES)) continue;
            int idx = (int)((acc[t][c][r]-lo)/denom*16.0f);   // reference op order
            idx = idx<0 ? 0 : (idx>15 ? 15 : idx);
            atomicAdd(&lh[idx*65 + lane], 1u);
          }
        }
      }
    }
  }
  if(!HIST){
    #pragma unroll
    for(int off=32; off; off>>=1){
      mMin = fminf(mMin, __shfl_down(mMin, off, 64));
      mMax = fmaxf(mMax, __shfl_down(mMax, off, 64));
    }
    if(lane==0){
      int slot = (blockIdx.x*4 + wv) & 63;
      atomicMin(&mmslot[slot],    f2ord(mMin));
      atomicMax(&mmslot[64+slot], f2ord(mMax));
    }
  } else {
    __syncthreads();
    if(threadIdx.x<16){
      unsigned s=0;
      for(int w=0;w<64;w++) s += lh[threadIdx.x*65+w];
      atomicAdd(&ghist[(blockIdx.x & 63)*16 + threadIdx.x], s);
    }
  }
}

__global__ void mmred_k(float* ws){
  unsigned* sl = (unsigned*)(ws + S_MMSLOT);
  unsigned* mm = (unsigned*)(ws + S_MM);
  int t = threadIdx.x;   // 64 threads
  unsigned mn = sl[t], mx = sl[64+t];
  #pragma unroll
  for(int off=32; off; off>>=1){
    mn = min(mn, (unsigned)__shfl_down((int)mn, off, 64));
    mx = max(mx, (unsigned)__shfl_down((int)mx, off, 64));
  }
  if(t==0){ mm[0]=mn; mm[1]=mx; }
}

// 128 blocks: [0,64) graph1, [64,128) graph2. Writes partials PC[128][32] (no atomics).
__global__ void colsum_k(const float* __restrict__ af1, const float* __restrict__ af2,
                         float* __restrict__ PC, int n){
  bool g2 = blockIdx.x >= 64;
  const float* af = g2 ? af2 : af1;
  int blk = blockIdx.x & 63;
  int f = threadIdx.x % 32;
  int rg = threadIdx.x / 32;
  float acc = 0.f;
  for(int node = blk*8 + rg; node < n; node += 64*8)
    acc += af[(size_t)node*32 + f];
  __shared__ float s[256];
  s[threadIdx.x]=acc; __syncthreads();
  if(threadIdx.x<32){
    float v=0.f;
    for(int r=0;r<8;r++) v += s[r*32+threadIdx.x];
    PC[(int)blockIdx.x*32 + threadIdx.x] = v;
  }
}

// 80 blocks: [0,40) graph1, [40,80) graph2. csum reduced from PC in-block;
// writes attention-pool partials PA[80][32] (no atomics). One node per thread.
__global__ __launch_bounds__(256) void attpool_k(const float* __restrict__ af1,
                                                 const float* __restrict__ af2,
                                                 const float* __restrict__ att_w,
                                                 const float* __restrict__ PC,
                                                 float* __restrict__ PA, int n){
  bool g2 = blockIdx.x >= 40;
  const float* af = g2 ? af2 : af1;
  int blk = g2 ? blockIdx.x-40 : blockIdx.x;
  int tid = threadIdx.x;
  __shared__ float scs[32], sgc[32], swv[128];
  if(tid<32){
    float cs = 0.f;
    const float* pc = PC + (g2 ? 64*32 : 0);
    for(int r=0;r<64;r++) cs += pc[r*32+tid];
    scs[tid] = cs;
  }
  __syncthreads();
  if(tid<32){
    float acc = 0.f;
    for(int f=0;f<32;f++) acc += scs[f]*att_w[f*32+tid];
    sgc[tid] = tanhf(acc * (1.0f/N_NODES));
  }
  __syncthreads();
  float pacc[32];
  #pragma unroll
  for(int f=0;f<32;f++) pacc[f]=0.f;
  int node = blk*256 + tid;
  if(node < n){
    const float* row = af + (size_t)node*32;
    float d = 0.f;
    #pragma unroll
    for(int f=0;f<32;f++) d += row[f]*sgc[f];
    float sig = 1.0f/(1.0f+expf(-d));
    #pragma unroll
    for(int f=0;f<32;f++) pacc[f] = row[f]*sig;
  }
  int wv = tid >> 6, lane = tid & 63;
  #pragma unroll
  for(int f=0;f<32;f++){
    float v = pacc[f];
    for(int off=32; off; off>>=1) v += __shfl_down(v, off, 64);
    if(lane==0) swv[wv*32+f] = v;
  }
  __syncthreads();
  if(tid<32)
    PA[(int)blockIdx.x*32 + tid] = swv[tid] + swv[32+tid] + swv[64+tid] + swv[96+tid];
}

// 80 blocks: [0,40) -> af1 with pv=p2 (PA rows 40..79) -> PT rows 0..39;
//            [40,80) -> af2 with pv=p1 (PA rows 0..39) -> PT rows 40..79.
__global__ __launch_bounds__(256) void tnmean_k(const float* __restrict__ af1,
                                                const float* __restrict__ af2,
                                                const float* __restrict__ tn_w,
                                                const float* __restrict__ tn_wb,
                                                const float* __restrict__ tn_bias,
                                                const float* __restrict__ PA,
                                                float* __restrict__ PT, int n){
  bool g2 = blockIdx.x >= 40;
  const float* X = g2 ? af2 : af1;
  int blk = g2 ? blockIdx.x-40 : blockIdx.x;
  int tid = threadIdx.x;
  __shared__ float spv[32];
  __shared__ float sB[512];
  __shared__ float sc[16];
  __shared__ float swn[64];
  if(tid<32){
    float s = 0.f;
    const float* pa = PA + (g2 ? 0 : 40*32);   // g1 blocks use p2, g2 blocks use p1
    for(int r=0;r<40;r++) s += pa[r*32+tid];
    spv[tid] = s;
  }
  __syncthreads();
  for(int e=tid; e<512; e+=256){
    int g = e/16, k = e%16;
    float acc = 0.f;
    for(int f=0;f<32;f++) acc += tn_w[(g*32+f)*16+k]*spv[f];
    sB[e] = acc + tn_wb[k*64+g];
  }
  if(tid<16){
    float acc = 0.f;
    for(int f=0;f<32;f++) acc += tn_wb[tid*64+32+f]*spv[f];
    sc[tid] = acc + tn_bias[tid];
  }
  __syncthreads();
  float a[16];
  #pragma unroll
  for(int k=0;k<16;k++) a[k]=0.f;
  int node = blk*256 + tid;
  if(node < n){
    const float* row = X + (size_t)node*32;
    float rv[32];
    #pragma unroll
    for(int g=0;g<32;g++) rv[g]=row[g];
    #pragma unroll
    for(int k=0;k<16;k++){
      float y = sc[k];
      #pragma unroll
      for(int g=0;g<32;g++) y += rv[g]*sB[g*16+k];
      a[k] = fmaxf(y, 0.f);
    }
  }
  int wv = tid >> 6, lane = tid & 63;
  #pragma unroll
  for(int k=0;k<16;k++){
    float v = a[k];
    for(int off=32; off; off>>=1) v += __shfl_down(v, off, 64);
    if(lane==0) swn[wv*16+k] = v;
  }
  __syncthreads();
  if(tid<16)
    PT[(int)blockIdx.x*16 + tid] = swn[tid] + swn[16+tid] + swn[32+tid] + swn[48+tid];
}

// parallel head: 64 threads, 1 block; reduces PA->p1/p2 and PT->s1/s2; s0 inline
__global__ void final_k(const float* __restrict__ PA, const float* __restrict__ PT,
                        const unsigned* __restrict__ ghist,
                        const float* __restrict__ tn_w, const float* __restrict__ tn_wb,
                        const float* __restrict__ tn_bias,
                        const float* __restrict__ fc1_w, const float* __restrict__ fc1_b,
                        const float* __restrict__ fc2_w, const float* __restrict__ fc2_b,
                        float* __restrict__ out){
  __shared__ float sp1[32], sp2[32];
  __shared__ float sc[64];
  __shared__ float hraw[16];
  __shared__ float sh[16];
  int t = threadIdx.x;
  const float invN = 1.0f/N_NODES;
  if(t<32){
    float s = 0.f;
    for(int r=0;r<40;r++) s += PA[r*32+t];
    sp1[t] = s;
  } else {
    int j = t-32;
    float s = 0.f;
    for(int r=40;r<80;r++) s += PA[r*32+j];
    sp2[j] = s;
  }
  __syncthreads();
  if(t<16){
    float s = 0.f;
    for(int f1=0;f1<32;f1++){
      float a = sp1[f1];
      for(int f2=0;f2<32;f2++) s += a*tn_w[(f1*32+f2)*16+t]*sp2[f2];
    }
    float blk = 0.f;
    for(int f=0;f<32;f++) blk += tn_wb[t*64+f]*sp1[f] + tn_wb[t*64+32+f]*sp2[f];
    sc[t] = fmaxf(s + blk + tn_bias[t], 0.f);
  }
  else if(t<32){
    int k = t-16;
    float s = 0.f;
    for(int r=0;r<40;r++) s += PT[r*16+k];
    sc[t] = s*invN;
  }
  else if(t<48){
    int k = t-32;
    float s = 0.f;
    for(int r=40;r<80;r++) s += PT[r*16+k];
    sc[t] = s*invN;
  }
  int bin = t & 15, grp = t >> 4;
  unsigned c = 0;
  for(int s=grp; s<64; s+=4) c += ghist[s*16+bin];
  c += (unsigned)__shfl_down((int)c, 32, 64);
  c += (unsigned)__shfl_down((int)c, 16, 64);
  if(t<16){
    float v = (float)c;
    if(v > 16777216.0f) v = 16777216.0f;   // fp32 +1.0 saturation emulation
    hraw[t] = v;
  }
  __syncthreads();
  if(t<16){
    float tot = 0.f;
    for(int b=0;b<16;b++) tot += hraw[b];   // same serial order as reference
    sc[48+t] = hraw[t]/tot;
  }
  __syncthreads();
  if(t<16){
    float a = fc1_b[t];
    for(int i=0;i<64;i++) a += sc[i]*fc1_w[i*16+t];
    sh[t] = fmaxf(a, 0.f);
  }
  __syncthreads();
  if(t==0){
    float o = fc2_b[0];
    for(int j=0;j<16;j++) o += sh[j]*fc2_w[j];
    out[0] = 1.0f/(1.0f+expf(-o));
  }
}

extern "C" void kernel_launch(void* const* d_in, const int* in_sizes, int n_in,
                              void* d_out, int out_size, void* d_ws, size_t ws_size,
                              hipStream_t stream){
  const float* x1      = (const float*)d_in[0];
  const float* x2      = (const float*)d_in[1];
  const int*   ei1     = (const int*)d_in[2];
  const int*   ei2     = (const int*)d_in[3];
  const float* W1      = (const float*)d_in[4];
  const float* b1      = (const float*)d_in[5];
  const float* W2      = (const float*)d_in[6];
  const float* b2      = (const float*)d_in[7];
  const float* W3      = (const float*)d_in[8];
  const float* b3      = (const float*)d_in[9];
  const float* att_w   = (const float*)d_in[10];
  const float* tn_w    = (const float*)d_in[11];
  const float* tn_wb   = (const float*)d_in[12];
  const float* tn_bias = (const float*)d_in[13];
  const float* fc1_w   = (const float*)d_in[14];
  const float* fc1_b   = (const float*)d_in[15];
  const float* fc2_w   = (const float*)d_in[16];
  const float* fc2_b   = (const float*)d_in[17];

  float* ws = (float*)d_ws;
  float* out = (float*)d_out;
  const int N = N_NODES, E = E_;

  bool big = ws_size >= WS_BIG_END*sizeof(float);

  size_t oCN1,oCN2,oDV1,oDV2,oIV1,oIV2,oOF1,oOF2,oCU1,oCU2,oSR1,oSR2,
         oCF1,oCF2,oBH1,oBH2,oBO1,oBO2,oAF1,oAF2;
  if(big){
    oCN1=2560;    oCN2=12560;   oDV1=22560;   oDV2=32560;
    oIV1=42560;   oIV2=52560;   oOF1=62560;   oOF2=72564;
    oCU1=82568;   oCU2=92568;   oSR1=102568;  oSR2=422568;
    oCF1=742568;  oCF2=1062568; oBH1=1382568; oBH2=2662568;
    oBO1=3942568; oBO2=5222568; oAF1=6502568; oAF2=6826152;
  } else {
    oCN1=2560;    oCN2=oCN1;    oDV1=12560;   oDV2=oDV1;
    oIV1=22560;   oIV2=oIV1;    oOF1=32560;   oOF2=oOF1;
    oCU1=42564;   oCU2=oCU1;    oSR1=52564;   oSR2=oSR1;
    oCF1=372564;  oCF2=oCF1;    oBH1=692564;  oBH2=oBH1;
    oBO1=1972564; oBO2=oBO1;    oAF1=3252564; oAF2=3576148;
  }
  int* cn1=(int*)(ws+oCN1); int* cn2=(int*)(ws+oCN2);
  float* dv1=ws+oDV1; float* dv2=ws+oDV2;
  float* iv1=ws+oIV1; float* iv2=ws+oIV2;
  int* of1=(int*)(ws+oOF1); int* of2=(int*)(ws+oOF2);
  int* cu1=(int*)(ws+oCU1); int* cu2=(int*)(ws+oCU2);
  int* sr1=(int*)(ws+oSR1); int* sr2=(int*)(ws+oSR2);
  float* cf1=ws+oCF1; float* cf2=ws+oCF2;
  float* bh1=ws+oBH1; float* bh2=ws+oBH2;
  float* bo1=ws+oBO1; float* bo2=ws+oBO2;
  float* af1=ws+oAF1; float* af2=ws+oAF2;
  // big: H lives in bo1 (dead after gemm3); small: in bh1 (dead after loop)
  unsigned short* Hbf = (unsigned short*)(big ? bo1 : bh1);
  // tail partials live in dead GCN scratch: big -> bh1, small -> bo1
  float* part = big ? bh1 : bo1;
  float* PC = part;                 // 128*32
  float* PA = part + 4096;          // 80*32
  float* PT = part + 4096 + 2560;   // 80*16

  unsigned* mmslot = (unsigned*)(ws + S_MMSLOT);
  unsigned* mm     = (unsigned*)(ws + S_MM);
  unsigned* ghist  = (unsigned*)(ws + S_HIST);

  const int BPG1 = 1250;   // gemm F=128 (ROWS=8)
  const int BPG2 = 625;    // gemm F=64
  const int BPG3 = 313;    // gemm F=32
  const int BA16 = 625;    // aggr GC=16 (16 nodes/block)
  const int BA8  = 313;    // aggr GC=8  (32 nodes/block)
  unsigned short* Z = (unsigned short*)0;

  init_k<<<(N+255)/256, 256, 0, stream>>>(ws, cn1, cn2, af1, af2);

  if(big){
    deg2_k<<<32, 256, 0, stream>>>(ei1+E, ei2+E, cn1, cn2, E);
    scan_k<<<2, 256, 0, stream>>>(cn1, dv1, iv1, of1, cu1,
                                  cn2, dv2, iv2, of2, cu2, N);
    bucket_k<<<(2*E+255)/256, 256, 0, stream>>>(ei1, ei2, cu1, cu2, dv1, dv2,
                                                sr1, sr2, cf1, cf2, E, 2*E);
    gemm_k<128,128,false><<<2*BPG1, 256, 0, stream>>>(x1, x2, W1, bh1, bh2, N, BPG1);
    aggr_k<16,32,false><<<BA16, 256, 0, stream>>>(bh1,bh1, of1,of1, sr1,sr1, cf1,cf1,
                                                  iv1,iv1, b1, bo1,bo1, Z,Z, N, BA16, 0);
    aggr_k<16,32,false><<<BA16, 256, 0, stream>>>(bh1,bh1, of1,of1, sr1,sr1, cf1,cf1,
                                                  iv1,iv1, b1, bo1,bo1, Z,Z, N, BA16, 16);
    aggr_k<16,32,false><<<BA16, 256, 0, stream>>>(bh2,bh2, of2,of2, sr2,sr2, cf2,cf2,
                                                  iv2,iv2, b1, bo2,bo2, Z,Z, N, BA16, 0);
    aggr_k<16,32,false><<<BA16, 256, 0, stream>>>(bh2,bh2, of2,of2, sr2,sr2, cf2,cf2,
                                                  iv2,iv2, b1, bo2,bo2, Z,Z, N, BA16, 16);
    gemm_k<128,64,true><<<2*BPG2, 256, 0, stream>>>(bo1, bo2, W2, bh1, bh2, N, BPG2);
    aggr_k<16,16,false><<<BA16, 256, 0, stream>>>(bh1,bh1, of1,of1, sr1,sr1, cf1,cf1,
                                                  iv1,iv1, b2, bo1,bo1, Z,Z, N, BA16, 0);
    aggr_k<16,16,false><<<BA16, 256, 0, stream>>>(bh2,bh2, of2,of2, sr2,sr2, cf2,cf2,
                                                  iv2,iv2, b2, bo2,bo2, Z,Z, N, BA16, 0);
    gemm_k<64,32,true><<<2*BPG3, 256, 0, stream>>>(bo1, bo2, W3, bh1, bh2, N, BPG3);
    aggr_k<8,8,true><<<2*BA8, 256, 0, stream>>>(bh1,bh2, of1,of2, sr1,sr2, cf1,cf2,
                                                iv1,iv2, b3, af1,af2,
                                                Hbf, Hbf + 2*(size_t)NAF, N, BA8, 0);
  } else {
    for(int g=0; g<2; g++){
      const float* x = g ? x2 : x1;
      const int* ei  = g ? ei2 : ei1;
      float* af      = g ? af2 : af1;
      if(g) zero_k<<<(N+255)/256, 256, 0, stream>>>(cn1, N);
      deg2_k<<<16, 256, 0, stream>>>(ei+E, ei+E, cn1, cn1, E);
      scan_k<<<1, 256, 0, stream>>>(cn1, dv1, iv1, of1, cu1,
                                    cn1, dv1, iv1, of1, cu1, N);
      bucket_k<<<(E+255)/256, 256, 0, stream>>>(ei, ei, cu1, cu1, dv1, dv1,
                                                sr1, sr1, cf1, cf1, E, E);
      gemm_k<128,128,false><<<BPG1, 256, 0, stream>>>(x, x, W1, bh1, bh1, N, BPG1);
      aggr_k<16,32,false><<<BA16, 256, 0, stream>>>(bh1,bh1, of1,of1, sr1,sr1, cf1,cf1,
                                                    iv1,iv1, b1, bo1,bo1, Z,Z, N, BA16, 0);
      aggr_k<16,32,false><<<BA16, 256, 0, stream>>>(bh1,bh1, of1,of1, sr1,sr1, cf1,cf1,
                                                    iv1,iv1, b1, bo1,bo1, Z,Z, N, BA16, 16);
      gemm_k<128,64,true><<<BPG2, 256, 0, stream>>>(bo1, bo1, W2, bh1, bh1, N, BPG2);
      aggr_k<16,16,false><<<BA16, 256, 0, stream>>>(bh1,bh1, of1,of1, sr1,sr1, cf1,cf1,
                                                    iv1,iv1, b2, bo1,bo1, Z,Z, N, BA16, 0);
      gemm_k<64,32,true><<<BPG3, 256, 0, stream>>>(bo1, bo1, W3, bh1, bh1, N, BPG3);
      aggr_k<8,8,false><<<BA8, 256, 0, stream>>>(bh1,bh1, of1,of1, sr1,sr1, cf1,cf1,
                                                 iv1,iv1, b3, af,af, Z,Z, N, BA8, 0);
    }
    cvt_k<<<(2*NAF+255)/256, 256, 0, stream>>>(af1, af2, Hbf);
  }

  // similarity on matrix cores: min/max pass -> slot reduce -> histogram pass
  simm_k<false><<<NT2*NJS, 256, 0, stream>>>(Hbf, mmslot, mm, ghist);
  mmred_k<<<1, 64, 0, stream>>>(ws);
  simm_k<true ><<<NT2*NJS, 256, 0, stream>>>(Hbf, mmslot, mm, ghist);

  // tail: partial-sum pipeline, no hot atomics
  colsum_k<<<128, 256, 0, stream>>>(af1, af2, PC, N);
  attpool_k<<<80, 256, 0, stream>>>(af1, af2, att_w, PC, PA, N);
  tnmean_k<<<80, 256, 0, stream>>>(af1, af2, tn_w, tn_wb, tn_bias, PA, PT, N);
  final_k<<<1, 64, 0, stream>>>(PA, PT, ghist, tn_w, tn_wb, tn_bias,
                                fc1_w, fc1_b, fc2_w, fc2_b, out);
}